// Round 4
// baseline (526.209 us; speedup 1.0000x reference)
//
#include <hip/hip_runtime.h>
#include <hip/hip_bf16.h>

// ---------- helpers ----------
typedef __attribute__((ext_vector_type(8))) short bf16x8;
typedef __attribute__((ext_vector_type(4))) float f32x4;

static __device__ __forceinline__ short f2bf(float f) {
    unsigned u = __float_as_uint(f);
    unsigned r = (u + 0x7FFFu + ((u >> 16) & 1u)) >> 16;  // RNE
    return (short)(unsigned short)r;
}
static __device__ __forceinline__ float bf2f(short s) {
    return __uint_as_float(((unsigned)(unsigned short)s) << 16);
}

// async global->LDS, 16B per lane; LDS dest = wave-uniform base + lane*16 (m104)
static __device__ __forceinline__ void gload16(const void* g, void* l) {
    __builtin_amdgcn_global_load_lds((const __attribute__((address_space(1))) unsigned int*)g,
                                     (__attribute__((address_space(3))) unsigned int*)l, 16, 0, 0);
}

// pack 8 fp32 -> bf16x8 (RNE packed cvt)
static __device__ __forceinline__ bf16x8 cvt8(const float4 lo, const float4 hi) {
    __hip_bfloat162 p0 = __float22bfloat162_rn(make_float2(lo.x, lo.y));
    __hip_bfloat162 p1 = __float22bfloat162_rn(make_float2(lo.z, lo.w));
    __hip_bfloat162 p2 = __float22bfloat162_rn(make_float2(hi.x, hi.y));
    __hip_bfloat162 p3 = __float22bfloat162_rn(make_float2(hi.z, hi.w));
    short2 s0 = *(short2*)&p0, s1 = *(short2*)&p1, s2 = *(short2*)&p2, s3 = *(short2*)&p3;
    bf16x8 r = {s0.x, s0.y, s1.x, s1.y, s2.x, s2.y, s3.x, s3.y};
    return r;
}

// ---------- degree / norm ----------
__global__ void deg_kernel(const int* __restrict__ src, const int* __restrict__ dst,
                           int* __restrict__ deg_out, int* __restrict__ deg_in, int E) {
    int e = blockIdx.x * blockDim.x + threadIdx.x;
    if (e < E) {
        atomicAdd(&deg_out[src[e]], 1);
        atomicAdd(&deg_in[dst[e]], 1);
    }
}

__global__ void norm_kernel(const int* __restrict__ deg_out, const int* __restrict__ deg_in,
                            float* __restrict__ ns, float* __restrict__ nd, int N) {
    int i = blockIdx.x * blockDim.x + threadIdx.x;
    if (i < N) {
        ns[i] = rsqrtf((float)max(deg_out[i], 1));
        nd[i] = rsqrtf((float)max(deg_in[i], 1));
    }
}

// ---------- 3-phase multi-block exclusive scan of deg_in -> offsets ----------
__global__ void scan_part1(const int* __restrict__ deg, int* __restrict__ bsum, int N) {
    __shared__ int red[256];
    int i = blockIdx.x * 256 + threadIdx.x;
    red[threadIdx.x] = (i < N) ? deg[i] : 0;
    __syncthreads();
    for (int off = 128; off > 0; off >>= 1) {
        if (threadIdx.x < off) red[threadIdx.x] += red[threadIdx.x + off];
        __syncthreads();
    }
    if (threadIdx.x == 0) bsum[blockIdx.x] = red[0];
}

__global__ void scan_part2(const int* __restrict__ bsum, int* __restrict__ bsum_ex, int NB,
                           int* __restrict__ offsets, int N, int E) {
    __shared__ int s[256];
    int t = threadIdx.x;
    int v = (t < NB) ? bsum[t] : 0;
    s[t] = v;
    __syncthreads();
    for (int off = 1; off < 256; off <<= 1) {
        int u = (t >= off) ? s[t - off] : 0;
        __syncthreads();
        s[t] += u;
        __syncthreads();
    }
    bsum_ex[t] = s[t] - v;  // exclusive
    if (t == 0) offsets[N] = E;
}

__global__ void scan_part3(const int* __restrict__ deg, const int* __restrict__ bsum_ex,
                           int* __restrict__ offsets, int N) {
    __shared__ int s[256];
    int t = threadIdx.x, i = blockIdx.x * 256 + t;
    int v = (i < N) ? deg[i] : 0;
    s[t] = v;
    __syncthreads();
    for (int off = 1; off < 256; off <<= 1) {
        int u = (t >= off) ? s[t - off] : 0;
        __syncthreads();
        s[t] += u;
        __syncthreads();
    }
    if (i < N) offsets[i] = bsum_ex[blockIdx.x] + s[t] - v;
}

// ---------- scatter edges into CSR-by-dst buckets ----------
__global__ void scatter_kernel(const int* __restrict__ src, const int* __restrict__ dst,
                               const int* __restrict__ offsets, int* __restrict__ cursor,
                               int* __restrict__ bucket, int E) {
    int e = blockIdx.x * blockDim.x + threadIdx.x;
    if (e < E) {
        int d = dst[e];
        int p = atomicAdd(&cursor[d], 1);
        bucket[offsets[d] + p] = src[e];
    }
}

// ---------- W1 [K=1024][N=256] fp32 -> Wt [n][k] bf16 ----------
__global__ __launch_bounds__(1024) void transpose_w1(const float* __restrict__ W1,
                                                     short* __restrict__ Wt) {
    __shared__ short tile[32][33];
    int k0 = blockIdx.x * 32, n0 = blockIdx.y * 32;
    int tx = threadIdx.x & 31, ty = threadIdx.x >> 5;
    tile[ty][tx] = f2bf(W1[(size_t)(k0 + ty) * 256 + (n0 + tx)]);
    __syncthreads();
    Wt[(size_t)(n0 + ty) * 1024 + (k0 + tx)] = tile[tx][ty];
}

// ---------- GEMM1: hb = bf16((x @ W1) * norm_src[row]) ----------
// BM=64 -> 1564 blocks (6.1/CU) for occupancy-driven latency hiding (m114).
// A: fp32 global -> VGPR -> pk-cvt -> bf16 ds_write (reg double-buffer, loads for
// k+1 in flight across tile k's MFMA). B: global_load_lds 16B, m97 layout.
#define BM 64
#define BN 128
#define BK 32
#define CSTR 136  // C-staging row stride in shorts

union SMem {
    struct {
        short A[BM * BK];  // 4 KB, row = 32 bf16 = 64 B
        short B[BN * BK];  // 8 KB, row = 32 bf16 = 64 B
    } s;
    short C[BM * CSTR];    // 17.4 KB epilogue staging
};

__global__ __launch_bounds__(256, 6) void gemm1_kernel(const float* __restrict__ x,
                                                       const short* __restrict__ Wt,
                                                       const float* __restrict__ norm_src,
                                                       short* __restrict__ hb, int M) {
    __shared__ __align__(16) SMem sm;
    __shared__ float ns_lds[BM];
    const int tid  = threadIdx.x;
    const int lane = tid & 63;
    const int wave = tid >> 6;
    const int quad = lane >> 4;
    const int mrow = lane & 15;
    const int wm = (wave >> 1) * 32;  // rows 0..31 / 32..63
    const int wn = (wave & 1) * 64;   // cols 0..63 / 64..127
    const int bm = blockIdx.x * BM;
    const int bn = blockIdx.y * BN;

    if (tid < BM) ns_lds[tid] = norm_src[min(bm + tid, M - 1)];

    f32x4 acc[2][4] = {};

    // A staging role: row = tid>>2 (0..63), chunk = tid&3 (8 fp32 -> 16B bf16)
    const int a_row = tid >> 2;
    const int a_chk = tid & 3;
    const float* a_src = x + (size_t)min(bm + a_row, M - 1) * 1024 + a_chk * 8;
    const bool a_ok = (bm + a_row < M);

    float4 a_lo, a_hi;
    a_lo = a_ok ? *(const float4*)(a_src + 0) : make_float4(0.f, 0.f, 0.f, 0.f);
    a_hi = a_ok ? *(const float4*)(a_src + 4) : make_float4(0.f, 0.f, 0.f, 0.f);

    for (int k0 = 0; k0 < 1024; k0 += BK) {
        // B: 2 gload16/wave, 16 rows each (contiguous, m104-safe)
#pragma unroll
        for (int i = 0; i < 2; i++) {
            int nbase = wave * 32 + i * 16;
            int n = nbase + (lane >> 2);
            gload16(Wt + (size_t)(bn + n) * 1024 + k0 + (lane & 3) * 8, &sm.s.B[nbase * 32]);
        }
        // A: cvt prefetched regs -> LDS
        *(bf16x8*)&sm.s.A[a_row * 32 + a_chk * 8] = cvt8(a_lo, a_hi);
        __syncthreads();  // drains B async loads + A writes

        // prefetch A for next tile (in flight across this tile's MFMA)
        if (k0 + BK < 1024) {
            a_lo = a_ok ? *(const float4*)(a_src + k0 + BK + 0) : make_float4(0.f, 0.f, 0.f, 0.f);
            a_hi = a_ok ? *(const float4*)(a_src + k0 + BK + 4) : make_float4(0.f, 0.f, 0.f, 0.f);
        }

        bf16x8 af[2], bfr[4];
#pragma unroll
        for (int mi = 0; mi < 2; mi++)
            af[mi] = *(const bf16x8*)&sm.s.A[(wm + mi * 16 + mrow) * 32 + quad * 8];
#pragma unroll
        for (int ni = 0; ni < 4; ni++)
            bfr[ni] = *(const bf16x8*)&sm.s.B[(wn + ni * 16 + mrow) * 32 + quad * 8];
#pragma unroll
        for (int mi = 0; mi < 2; mi++)
#pragma unroll
            for (int ni = 0; ni < 4; ni++)
                acc[mi][ni] = __builtin_amdgcn_mfma_f32_16x16x32_bf16(af[mi], bfr[ni], acc[mi][ni], 0, 0, 0);
        __syncthreads();  // all waves done with tile before overwrite
    }

    // epilogue: acc -> C LDS (scaled, bf16), then coalesced 16B/lane stores
#pragma unroll
    for (int mi = 0; mi < 2; mi++) {
#pragma unroll
        for (int reg = 0; reg < 4; reg++) {
            int row = wm + mi * 16 + quad * 4 + reg;
            float nsv = ns_lds[row];
#pragma unroll
            for (int ni = 0; ni < 4; ni++) {
                int col = wn + ni * 16 + mrow;
                sm.C[row * CSTR + col] = f2bf(acc[mi][ni][reg] * nsv);
            }
        }
    }
    __syncthreads();
    // 64 rows x 128 cols bf16: 16 rows/pass (16 chunks of 16B per row-half)
#pragma unroll
    for (int j = 0; j < 4; j++) {
        int row = (tid >> 4) + j * 16;
        int chunk = tid & 15;
        if (bm + row < M) {
            int4 v = *(const int4*)&sm.C[row * CSTR + chunk * 8];
            *(int4*)(hb + (size_t)(bm + row) * 256 + bn + chunk * 8) = v;
        }
    }
}

// ---------- agg1 fused with layer-2 projection ----------
__global__ __launch_bounds__(256) void agg1_kernel(const short* __restrict__ hb,
                                                   const int* __restrict__ bucket,
                                                   const int* __restrict__ offsets,
                                                   const float* __restrict__ norm_dst,
                                                   const float* __restrict__ norm_src,
                                                   const float* __restrict__ b1,
                                                   const float* __restrict__ W2,
                                                   float* __restrict__ z, int N) {
    int wave = threadIdx.x >> 6;
    int lane = threadIdx.x & 63;
    int node = blockIdx.x * 4 + wave;
    if (node >= N) return;
    int beg = offsets[node], end = offsets[node + 1];
    float a0 = 0.f, a1 = 0.f, a2 = 0.f, a3 = 0.f;
    int e = beg;
    for (; e + 7 < end; e += 8) {  // 8 gathers in flight
        short4 v[8];
#pragma unroll
        for (int j = 0; j < 8; j++)
            v[j] = *(const short4*)(hb + (size_t)bucket[e + j] * 256 + lane * 4);
#pragma unroll
        for (int j = 0; j < 8; j++) {
            a0 += bf2f(v[j].x); a1 += bf2f(v[j].y);
            a2 += bf2f(v[j].z); a3 += bf2f(v[j].w);
        }
    }
    for (; e < end; e++) {
        short4 v0 = *(const short4*)(hb + (size_t)bucket[e] * 256 + lane * 4);
        a0 += bf2f(v0.x); a1 += bf2f(v0.y); a2 += bf2f(v0.z); a3 += bf2f(v0.w);
    }
    float nd = norm_dst[node];
    float4 bb = *(const float4*)(b1 + lane * 4);
    float o0 = fmaxf(a0 * nd + bb.x, 0.f);
    float o1 = fmaxf(a1 * nd + bb.y, 0.f);
    float o2 = fmaxf(a2 * nd + bb.z, 0.f);
    float o3 = fmaxf(a3 * nd + bb.w, 0.f);
    float4 w = *(const float4*)(W2 + lane * 4);
    float p = o0 * w.x + o1 * w.y + o2 * w.z + o3 * w.w;
#pragma unroll
    for (int off = 32; off > 0; off >>= 1) p += __shfl_xor(p, off, 64);
    if (lane == 0) z[node] = p * norm_src[node];
}

// ---------- agg2: out = relu(norm_dst * sum z[src] + b2) ----------
__global__ void agg2_kernel(const float* __restrict__ z, const int* __restrict__ bucket,
                            const int* __restrict__ offsets, const float* __restrict__ norm_dst,
                            const float* __restrict__ b2, float* __restrict__ out, int N) {
    int i = blockIdx.x * blockDim.x + threadIdx.x;
    if (i >= N) return;
    int beg = offsets[i], end = offsets[i + 1];
    float s = 0.f;
    for (int e = beg; e < end; e++) s += z[bucket[e]];
    out[i] = fmaxf(s * norm_dst[i] + b2[0], 0.f);
}

extern "C" void kernel_launch(void* const* d_in, const int* in_sizes, int n_in,
                              void* d_out, int out_size, void* d_ws, size_t ws_size,
                              hipStream_t stream) {
    const int D_HID = in_sizes[4];           // 256
    const int D_IN  = in_sizes[3] / D_HID;   // 1024
    const int N     = in_sizes[0] / D_IN;    // 50000
    const int E     = in_sizes[1];           // 800000

    const float* x   = (const float*)d_in[0];
    const int*   src = (const int*)d_in[1];
    const int*   dst = (const int*)d_in[2];
    const float* W1  = (const float*)d_in[3];
    const float* b1  = (const float*)d_in[4];
    const float* W2  = (const float*)d_in[5];
    const float* b2  = (const float*)d_in[6];
    float* out = (float*)d_out;

    char* p = (char*)d_ws;
    auto alloc = [&](size_t bytes) {
        void* r = (void*)p;
        p += (bytes + 255) & ~(size_t)255;
        return r;
    };
    int*   deg_out  = (int*)alloc((size_t)N * 4);
    int*   deg_in   = (int*)alloc((size_t)N * 4);
    int*   cursor   = (int*)alloc((size_t)N * 4);
    float* norm_src = (float*)alloc((size_t)N * 4);
    float* norm_dst = (float*)alloc((size_t)N * 4);
    int*   offsets  = (int*)alloc((size_t)(N + 1) * 4);
    int*   bucket   = (int*)alloc((size_t)E * 4);
    short* Wt       = (short*)alloc((size_t)D_IN * D_HID * 2);
    short* hb       = (short*)alloc((size_t)N * D_HID * 2);
    float* z        = (float*)alloc((size_t)N * 4);
    int*   bsum     = (int*)alloc(256 * 4);
    int*   bsum_ex  = (int*)alloc(256 * 4);

    const int NB = (N + 255) / 256;  // 196 scan blocks

    hipMemsetAsync(deg_out, 0, (size_t)N * 4, stream);
    hipMemsetAsync(deg_in,  0, (size_t)N * 4, stream);
    hipMemsetAsync(cursor,  0, (size_t)N * 4, stream);

    deg_kernel<<<(E + 255) / 256, 256, 0, stream>>>(src, dst, deg_out, deg_in, E);
    norm_kernel<<<(N + 255) / 256, 256, 0, stream>>>(deg_out, deg_in, norm_src, norm_dst, N);
    scan_part1<<<NB, 256, 0, stream>>>(deg_in, bsum, N);
    scan_part2<<<1, 256, 0, stream>>>(bsum, bsum_ex, NB, offsets, N, E);
    scan_part3<<<NB, 256, 0, stream>>>(deg_in, bsum_ex, offsets, N);
    scatter_kernel<<<(E + 255) / 256, 256, 0, stream>>>(src, dst, offsets, cursor, bucket, E);
    transpose_w1<<<dim3(D_IN / 32, D_HID / 32), 1024, 0, stream>>>(W1, Wt);
    gemm1_kernel<<<dim3((N + BM - 1) / BM, D_HID / BN), 256, 0, stream>>>(x, Wt, norm_src, hb, N);
    agg1_kernel<<<(N + 3) / 4, 256, 0, stream>>>(hb, bucket, offsets, norm_dst, norm_src, b1, W2, z, N);
    agg2_kernel<<<(N + 255) / 256, 256, 0, stream>>>(z, bucket, offsets, norm_dst, b2, out, N);
}